// Round 12
// baseline (203.594 us; speedup 1.0000x reference)
//
#include <hip/hip_runtime.h>

// Problem constants
constexpr int TB = 16;        // batch
constexpr int NP = 2048;      // pre neurons
constexpr int NQ = 2048;      // post neurons
constexpr int TT = 256;       // timesteps
constexpr int KH = TB * TT;   // 4096, half-K
constexpr int KT = 2 * KH;    // 8192, total contraction length

typedef unsigned short ushort_t;
typedef __attribute__((ext_vector_type(8))) __bf16 bf16x8;
typedef __attribute__((ext_vector_type(4))) float f32x4;

// bf16 round-to-nearest-even, as uint (inputs finite)
__device__ __forceinline__ unsigned bf1(float f) {
    unsigned u = __builtin_bit_cast(unsigned, f);
    return (u + 0x7FFFu + ((u >> 16) & 1u)) >> 16;
}
__device__ __forceinline__ unsigned pack2(float lo, float hi) {
    return bf1(lo) | (bf1(hi) << 16);
}
__device__ __forceinline__ unsigned spk2(float a, float b) {
    return ((a != 0.f) ? 0x3F80u : 0u) | ((b != 0.f) ? 0x3F800000u : 0u);
}

// Decay powers
constexpr float DF1 = 0.95122942450071400910f;            // exp(-0.05)
constexpr float DF2 = DF1 * DF1;
constexpr float DF4 = DF2 * DF2;
constexpr float DF8 = DF4 * DF4;
constexpr float DF16 = DF8 * DF8;
constexpr float DF32 = DF16 * DF16;
constexpr float DF64 = DF32 * DF32;

constexpr float DX1 = 0.99014786386058731819f;            // exp(-1/101)
constexpr float DX2 = DX1 * DX1;
constexpr float DX4 = DX2 * DX2;
constexpr float DX8 = DX4 * DX4;
constexpr float DX16 = DX8 * DX8;
constexpr float DX32 = DX16 * DX16;
constexpr float DX64 = DX32 * DX32;

template <int K>
__device__ __forceinline__ float seg_step(float b, float pw, int sl) {
    float t = __shfl_up(b, K, 64);
    return (sl >= K) ? fmaf(pw, t, b) : b;
}
__device__ __forceinline__ float scan16(float c, float p1, float p2, float p4,
                                        float p8, int sl) {
    c = seg_step<1>(c, p1, sl);
    c = seg_step<2>(c, p2, sl);
    c = seg_step<4>(c, p4, sl);
    c = seg_step<8>(c, p8, sl);
    return c;
}
__device__ __forceinline__ float fold4(float4 u, float d) {
    float C = d * u.x;
    C = d * (C + u.y); C = d * (C + u.z); C = d * (C + u.w);
    return C;
}
__device__ __forceinline__ float4 expand4(float x, float4 u, float d) {
    float4 t;
    t.x = x; x = d * (x + u.x);
    t.y = x; x = d * (x + u.y);
    t.z = x; x = d * (x + u.z);
    t.w = x;
    return t;
}

// ---------------------------------------------------------------------------
// Stage 1a: PRE rows only (light path: one trace + spike copy).
// Split from the dual-path kernel: the combined kernel's worst-case register
// footprint (union of both paths) matched the spill signature (r2 VGPR=12).
// 16 lanes per row; lane sl owns timesteps 64j+4sl..+3, j=0..3.
// ---------------------------------------------------------------------------
__global__ __launch_bounds__(256) void stage_pre(
    const float* __restrict__ pre, ushort_t* __restrict__ Ab,
    float* __restrict__ partials)
{
    const int tid  = threadIdx.x;
    const int lane = tid & 63;
    const int wv   = tid >> 6;
    const int sl   = lane & 15;
    const int m    = blockIdx.x * 16 + wv * 4 + (lane >> 4);   // 0..32767
    const int b = m >> 11;
    const int r = m & 2047;

    const float4* srcRow = (const float4*)(pre + (size_t)m * TT);
    const float4 u0 = srcRow[sl];
    const float4 u1 = srcRow[16 + sl];
    const float4 u2 = srcRow[32 + sl];
    const float4 u3 = srcRow[48 + sl];

    float cnt = ((u0.x + u0.y) + (u0.z + u0.w)) + ((u1.x + u1.y) + (u1.z + u1.w))
              + ((u2.x + u2.y) + (u2.z + u2.w)) + ((u3.x + u3.y) + (u3.z + u3.w));

    const int hi = lane | 15;

    float bf0 = scan16(fold4(u0, DF1), DF4, DF8, DF16, DF32, sl);
    float bf1_ = scan16(fold4(u1, DF1), DF4, DF8, DF16, DF32, sl);
    float bf2 = scan16(fold4(u2, DF1), DF4, DF8, DF16, DF32, sl);
    float bf3 = scan16(fold4(u3, DF1), DF4, DF8, DF16, DF32, sl);
    const float Tf0 = __shfl(bf0, hi, 64);
    const float Tf1 = __shfl(bf1_, hi, 64);
    const float Tf2 = __shfl(bf2, hi, 64);
    const float Xf1 = Tf0;
    const float Xf2 = fmaf(DF64, Xf1, Tf1);
    const float Xf3 = fmaf(DF64, Xf2, Tf2);
    float ef0 = __shfl_up(bf0, 1, 64);
    float ef1 = __shfl_up(bf1_, 1, 64);
    float ef2 = __shfl_up(bf2, 1, 64);
    float ef3 = __shfl_up(bf3, 1, 64);
    if (sl == 0) { ef0 = 0.f; ef1 = 0.f; ef2 = 0.f; ef3 = 0.f; }
    float pf = 1.f;
    if (sl & 1) pf *= DF4;
    if (sl & 2) pf *= DF8;
    if (sl & 4) pf *= DF16;
    if (sl & 8) pf *= DF32;
    const float4 t0 = expand4(ef0,                 u0, DF1);
    const float4 t1 = expand4(fmaf(pf, Xf1, ef1),  u1, DF1);
    const float4 t2 = expand4(fmaf(pf, Xf2, ef2),  u2, DF1);
    const float4 t3 = expand4(fmaf(pf, Xf3, ef3),  u3, DF1);

    ushort_t* oA = Ab + (size_t)r * KT + b * TT + 4 * sl;

    *(uint2*)(oA)            = uint2{pack2(t0.x, t0.y), pack2(t0.z, t0.w)};
    *(uint2*)(oA + 64)       = uint2{pack2(t1.x, t1.y), pack2(t1.z, t1.w)};
    *(uint2*)(oA + 128)      = uint2{pack2(t2.x, t2.y), pack2(t2.z, t2.w)};
    *(uint2*)(oA + 192)      = uint2{pack2(t3.x, t3.y), pack2(t3.z, t3.w)};
    *(uint2*)(oA + KH)       = uint2{spk2(u0.x, u0.y), spk2(u0.z, u0.w)};
    *(uint2*)(oA + KH + 64)  = uint2{spk2(u1.x, u1.y), spk2(u1.z, u1.w)};
    *(uint2*)(oA + KH + 128) = uint2{spk2(u2.x, u2.y), spk2(u2.z, u2.w)};
    *(uint2*)(oA + KH + 192) = uint2{spk2(u3.x, u3.y), spk2(u3.z, u3.w)};

    #pragma unroll
    for (int off = 32; off > 0; off >>= 1)
        cnt += __shfl_down(cnt, off, 64);
    __shared__ float wsum[4];
    if (lane == 0) wsum[wv] = cnt;
    __syncthreads();
    if (tid == 0)
        partials[blockIdx.x] = (wsum[0] + wsum[1]) + (wsum[2] + wsum[3]);
}

// ---------------------------------------------------------------------------
// Stage 1b: POST rows only (heavy path: two traces, gated A-col, LTD B-col).
// ---------------------------------------------------------------------------
__global__ __launch_bounds__(256) void stage_post(
    const float* __restrict__ post,
    const float* __restrict__ mApP, const float* __restrict__ mAmP,
    ushort_t* __restrict__ Bb, float* __restrict__ partials)
{
    const int tid  = threadIdx.x;
    const int lane = tid & 63;
    const int wv   = tid >> 6;
    const int sl   = lane & 15;
    const int m    = blockIdx.x * 16 + wv * 4 + (lane >> 4);   // 0..32767
    const int b = m >> 11;
    const int r = m & 2047;

    const float4* srcRow = (const float4*)(post + (size_t)m * TT);
    const float4 u0 = srcRow[sl];
    const float4 u1 = srcRow[16 + sl];
    const float4 u2 = srcRow[32 + sl];
    const float4 u3 = srcRow[48 + sl];

    float cnt = ((u0.x + u0.y) + (u0.z + u0.w)) + ((u1.x + u1.y) + (u1.z + u1.w))
              + ((u2.x + u2.y) + (u2.z + u2.w)) + ((u3.x + u3.y) + (u3.z + u3.w));

    const int hi = lane | 15;

    // fast trace (x_post)
    float bf0 = scan16(fold4(u0, DF1), DF4, DF8, DF16, DF32, sl);
    float bf1_ = scan16(fold4(u1, DF1), DF4, DF8, DF16, DF32, sl);
    float bf2 = scan16(fold4(u2, DF1), DF4, DF8, DF16, DF32, sl);
    float bf3 = scan16(fold4(u3, DF1), DF4, DF8, DF16, DF32, sl);
    const float Tf0 = __shfl(bf0, hi, 64);
    const float Tf1 = __shfl(bf1_, hi, 64);
    const float Tf2 = __shfl(bf2, hi, 64);
    const float Xf1 = Tf0;
    const float Xf2 = fmaf(DF64, Xf1, Tf1);
    const float Xf3 = fmaf(DF64, Xf2, Tf2);
    float ef0 = __shfl_up(bf0, 1, 64);
    float ef1 = __shfl_up(bf1_, 1, 64);
    float ef2 = __shfl_up(bf2, 1, 64);
    float ef3 = __shfl_up(bf3, 1, 64);
    if (sl == 0) { ef0 = 0.f; ef1 = 0.f; ef2 = 0.f; ef3 = 0.f; }
    float pf = 1.f;
    if (sl & 1) pf *= DF4;
    if (sl & 2) pf *= DF8;
    if (sl & 4) pf *= DF16;
    if (sl & 8) pf *= DF32;
    const float4 t0 = expand4(ef0,                 u0, DF1);
    const float4 t1 = expand4(fmaf(pf, Xf1, ef1),  u1, DF1);
    const float4 t2 = expand4(fmaf(pf, Xf2, ef2),  u2, DF1);
    const float4 t3 = expand4(fmaf(pf, Xf3, ef3),  u3, DF1);

    ushort_t* oA = Bb + (size_t)r * KT + b * TT + 4 * sl;
    const float Am = *mAmP;

    // write LTD column first to retire t0..t3 registers early
    *(uint2*)(oA + KH)       = uint2{pack2(-Am * t0.x, -Am * t0.y), pack2(-Am * t0.z, -Am * t0.w)};
    *(uint2*)(oA + KH + 64)  = uint2{pack2(-Am * t1.x, -Am * t1.y), pack2(-Am * t1.z, -Am * t1.w)};
    *(uint2*)(oA + KH + 128) = uint2{pack2(-Am * t2.x, -Am * t2.y), pack2(-Am * t2.z, -Am * t2.w)};
    *(uint2*)(oA + KH + 192) = uint2{pack2(-Am * t3.x, -Am * t3.y), pack2(-Am * t3.z, -Am * t3.w)};

    // slow (triplet) trace
    float bx0 = scan16(fold4(u0, DX1), DX4, DX8, DX16, DX32, sl);
    float bx1 = scan16(fold4(u1, DX1), DX4, DX8, DX16, DX32, sl);
    float bx2 = scan16(fold4(u2, DX1), DX4, DX8, DX16, DX32, sl);
    float bx3 = scan16(fold4(u3, DX1), DX4, DX8, DX16, DX32, sl);
    const float Tx0 = __shfl(bx0, hi, 64);
    const float Tx1 = __shfl(bx1, hi, 64);
    const float Tx2 = __shfl(bx2, hi, 64);
    const float Xx1 = Tx0;
    const float Xx2 = fmaf(DX64, Xx1, Tx1);
    const float Xx3 = fmaf(DX64, Xx2, Tx2);
    float ex0 = __shfl_up(bx0, 1, 64);
    float ex1 = __shfl_up(bx1, 1, 64);
    float ex2 = __shfl_up(bx2, 1, 64);
    float ex3 = __shfl_up(bx3, 1, 64);
    if (sl == 0) { ex0 = 0.f; ex1 = 0.f; ex2 = 0.f; ex3 = 0.f; }
    float px = 1.f;
    if (sl & 1) px *= DX4;
    if (sl & 2) px *= DX8;
    if (sl & 4) px *= DX16;
    if (sl & 8) px *= DX32;
    const float4 w0 = expand4(ex0,                u0, DX1);
    const float4 w1 = expand4(fmaf(px, Xx1, ex1), u1, DX1);
    const float4 w2 = expand4(fmaf(px, Xx2, ex2), u2, DX1);
    const float4 w3 = expand4(fmaf(px, Xx3, ex3), u3, DX1);

    const float Ap = *mApP;
    auto av2 = [&](float sa, float ta, float sb, float tb) -> unsigned {
        unsigned lo = (sa != 0.f) ? bf1(fmaf(0.0065f, ta, Ap)) : 0u;
        unsigned hi2 = (sb != 0.f) ? bf1(fmaf(0.0065f, tb, Ap)) : 0u;
        return lo | (hi2 << 16);
    };
    *(uint2*)(oA)       = uint2{av2(u0.x, w0.x, u0.y, w0.y), av2(u0.z, w0.z, u0.w, w0.w)};
    *(uint2*)(oA + 64)  = uint2{av2(u1.x, w1.x, u1.y, w1.y), av2(u1.z, w1.z, u1.w, w1.w)};
    *(uint2*)(oA + 128) = uint2{av2(u2.x, w2.x, u2.y, w2.y), av2(u2.z, w2.z, u2.w, w2.w)};
    *(uint2*)(oA + 192) = uint2{av2(u3.x, w3.x, u3.y, w3.y), av2(u3.z, w3.z, u3.w, w3.w)};

    #pragma unroll
    for (int off = 32; off > 0; off >>= 1)
        cnt += __shfl_down(cnt, off, 64);
    __shared__ float wsum[4];
    if (lane == 0) wsum[wv] = cnt;
    __syncthreads();
    if (tid == 0)
        partials[2048 + blockIdx.x] = (wsum[0] + wsum[1]) + (wsum[2] + wsum[3]);
}

// ---------------------------------------------------------------------------
// Stage 2: r9's proven GEMM (split-K=2, BK=64, dbuf, hoisted pointers, XCD
// swizzle, 0 LDS conflicts) + block-0 spike-count reduction -> scaleBuf.
// Partials: z=0 -> d_out, z=1 -> ws.
// ---------------------------------------------------------------------------
__device__ __forceinline__ void async16(const ushort_t* g, ushort_t* l) {
    __builtin_amdgcn_global_load_lds(
        (const __attribute__((address_space(1))) unsigned int*)g,
        (__attribute__((address_space(3))) unsigned int*)l,
        16, 0, 0);
}

__global__ __launch_bounds__(256, 2) void gemm_split(
    const ushort_t* __restrict__ Ab, const ushort_t* __restrict__ Bb,
    const float* __restrict__ sp, float* __restrict__ scaleBuf,
    float* __restrict__ P0, float* __restrict__ P1)
{
    __shared__ ushort_t As[2][128 * 64];
    __shared__ ushort_t Bs[2][128 * 64];
    __shared__ float red[4];

    const int tid  = threadIdx.x;
    const int lane = tid & 63;
    const int wv   = tid >> 6;
    const int wr   = wv >> 1;
    const int wc   = wv & 1;
    const int quad = lane >> 4;
    const int m16  = lane & 15;

    // block 0: reduce the 4096 spike-count partials -> scale
    if (blockIdx.x == 0) {
        float v = 0.f;
        #pragma unroll
        for (int i = 0; i < 16; ++i) v += sp[tid + i * 256];
        #pragma unroll
        for (int off = 32; off > 0; off >>= 1)
            v += __shfl_down(v, off, 64);
        if (lane == 0) red[wv] = v;
        __syncthreads();
        if (tid == 0) {
            float s = (red[0] + red[1]) + (red[2] + red[3]);
            scaleBuf[0] = sqrtf(0.1f / (s * (1.0f / 4096.0f) + 1e-6f));
        }
    }

    // XCD swizzle: id&7 = XCD; fixed 4x8 (p,q) patch per XCD, z inner
    const int id  = blockIdx.x;
    const int xcd = id & 7;
    const int j5  = id >> 3;          // 0..63
    const int z   = j5 & 1;
    const int t   = j5 >> 1;          // 0..31
    const int pt  = ((xcd >> 1) << 2) + (t >> 3);   // 0..15
    const int qt  = ((xcd & 1) << 3) + (t & 7);     // 0..15

    const int p0 = pt * 128;
    const int q0 = qt * 128;
    const int kbase = z * (KT / 2);
    const int ldsbase = wv * 512;     // elements; wave-uniform

    const ushort_t* gaP[4];
    const ushort_t* gbP[4];
    #pragma unroll
    for (int rr = 0; rr < 4; ++rr) {
        const int c   = rr * 256 + tid;
        const int row = c >> 3;
        const int kk8 = (c & 7) ^ (row & 7);
        gaP[rr] = Ab + (size_t)(p0 + row) * KT + kbase + kk8 * 8;
        gbP[rr] = Bb + (size_t)(q0 + row) * KT + kbase + kk8 * 8;
    }

    f32x4 acc[4][4] = {};

    auto stageF = [&](int buf) {
        #pragma unroll
        for (int rr = 0; rr < 4; ++rr) {
            async16(gaP[rr], &As[buf][rr * 2048 + ldsbase]);
            async16(gbP[rr], &Bs[buf][rr * 2048 + ldsbase]);
            gaP[rr] += 64;
            gbP[rr] += 64;
        }
    };
    auto computeF = [&](int buf) {
        #pragma unroll
        for (int ks = 0; ks < 2; ++ks) {
            bf16x8 af[4], bfr[4];
            #pragma unroll
            for (int i = 0; i < 4; ++i) {
                const int row  = wr * 64 + i * 16 + m16;
                const int slot = (ks * 4 + quad) ^ (row & 7);
                af[i] = *(const bf16x8*)&As[buf][row * 64 + slot * 8];
            }
            #pragma unroll
            for (int jj = 0; jj < 4; ++jj) {
                const int row  = wc * 64 + jj * 16 + m16;
                const int slot = (ks * 4 + quad) ^ (row & 7);
                bfr[jj] = *(const bf16x8*)&Bs[buf][row * 64 + slot * 8];
            }
            #pragma unroll
            for (int i = 0; i < 4; ++i)
                #pragma unroll
                for (int jj = 0; jj < 4; ++jj)
                    acc[i][jj] = __builtin_amdgcn_mfma_f32_16x16x32_bf16(
                        af[i], bfr[jj], acc[i][jj], 0, 0, 0);
        }
    };

    constexpr int NIT = (KT / 2) / 64;   // 64 k-chunks, 32 double-iters
    stageF(0);
    for (int kt2 = 0; kt2 < NIT / 2; ++kt2) {
        __syncthreads();
        stageF(1);
        computeF(0);
        __syncthreads();
        if (kt2 + 1 < NIT / 2)
            stageF(0);
        computeF(1);
    }

    float* P = z ? P1 : P0;
    #pragma unroll
    for (int i = 0; i < 4; ++i) {
        const int prow = p0 + wr * 64 + i * 16 + quad * 4;
        #pragma unroll
        for (int jj = 0; jj < 4; ++jj) {
            const int qcol = q0 + wc * 64 + jj * 16 + m16;
            #pragma unroll
            for (int r2 = 0; r2 < 4; ++r2)
                P[(size_t)(prow + r2) * NQ + qcol] = acc[i][jj][r2];
        }
    }
}

// ---------------------------------------------------------------------------
// Stage 3: Out = clip(W + scale*(P0+P1), -2, 2); P0 lives in d_out (in-place).
// ---------------------------------------------------------------------------
__global__ __launch_bounds__(256) void merge_out(
    const float* __restrict__ W, const float* __restrict__ P1,
    const float* __restrict__ scaleBuf, float* __restrict__ Out)
{
    const float scale = scaleBuf[0];
    const size_t i4 = (size_t)blockIdx.x * 256 + threadIdx.x;
    float4 w = ((const float4*)W)[i4];
    float4 a = ((const float4*)Out)[i4];
    float4 c = ((const float4*)P1)[i4];
    float4 o;
    o.x = fminf(fmaxf(fmaf(scale, a.x + c.x, w.x), -2.f), 2.f);
    o.y = fminf(fmaxf(fmaf(scale, a.y + c.y, w.y), -2.f), 2.f);
    o.z = fminf(fmaxf(fmaf(scale, a.z + c.z, w.z), -2.f), 2.f);
    o.w = fminf(fmaxf(fmaf(scale, a.w + c.w, w.w), -2.f), 2.f);
    ((float4*)Out)[i4] = o;
}

extern "C" void kernel_launch(void* const* d_in, const int* in_sizes, int n_in,
                              void* d_out, int out_size, void* d_ws, size_t ws_size,
                              hipStream_t stream) {
    const float* pre  = (const float*)d_in[0];
    const float* post = (const float*)d_in[1];
    const float* W    = (const float*)d_in[2];
    const float* mAp  = (const float*)d_in[3];
    const float* mAm  = (const float*)d_in[4];
    float* out = (float*)d_out;

    char* ws = (char*)d_ws;
    float* partials = (float*)ws;                                    // 16 KB (4096 slots)
    float* scaleBuf = (float*)(ws + 16384);
    ushort_t* Ab = (ushort_t*)(ws + 32768);                          // 33.6 MB
    ushort_t* Bb = (ushort_t*)(ws + 32768 + (size_t)NP * KT * 2);    // 33.6 MB
    float* P1    = (float*)(ws + 32768 + 2 * (size_t)NP * KT * 2);   // 16.8 MB

    stage_pre<<<dim3(TB * NP / 16), dim3(256), 0, stream>>>(
        pre, Ab, partials);

    stage_post<<<dim3(TB * NQ / 16), dim3(256), 0, stream>>>(
        post, mAp, mAm, Bb, partials);

    gemm_split<<<dim3(512), dim3(256), 0, stream>>>(
        Ab, Bb, partials, scaleBuf, out, P1);

    merge_out<<<dim3(NP * NQ / 1024), dim3(256), 0, stream>>>(
        W, P1, scaleBuf, out);
}

// Round 13
// 199.526 us; speedup vs baseline: 1.0204x; 1.0204x over previous
//
#include <hip/hip_runtime.h>

// ============================================================================
// STDP plasticity — final configuration (best measured: 199.6 us, r9).
// Ledger: stage ~60-70 us (HBM floor 53 us: 268 MB fp32 spike read + 67 MB
// bf16 write), gemm 76 us (= 904 TF effective, the m97-structure plateau;
// split-K=2, BK=64, dbuf prefetch, XCD swizzle, 0 LDS conflicts), merge 11 us
// (its BW floor), ~36 us fixed dispatch/graph overhead.
// Closed branches (measured): fused epilogue via device flags (r4, +126 us),
// cooperative grid-sync (r8, fails capture), BK=32 split-K=4 (r7, 8.4M LDS
// conflicts), single fused 512-thread GEMM+merge (r10/r11, +3 us), stage
// pre/post split (r12, +4 us).
// ============================================================================

// Problem constants
constexpr int TB = 16;        // batch
constexpr int NP = 2048;      // pre neurons
constexpr int NQ = 2048;      // post neurons
constexpr int TT = 256;       // timesteps
constexpr int KH = TB * TT;   // 4096, half-K
constexpr int KT = 2 * KH;    // 8192, total contraction length

typedef unsigned short ushort_t;
typedef __attribute__((ext_vector_type(8))) __bf16 bf16x8;
typedef __attribute__((ext_vector_type(4))) float f32x4;

// bf16 round-to-nearest-even, as uint (inputs finite)
__device__ __forceinline__ unsigned bf1(float f) {
    unsigned u = __builtin_bit_cast(unsigned, f);
    return (u + 0x7FFFu + ((u >> 16) & 1u)) >> 16;
}
__device__ __forceinline__ unsigned pack2(float lo, float hi) {
    return bf1(lo) | (bf1(hi) << 16);
}
__device__ __forceinline__ unsigned spk2(float a, float b) {
    return ((a != 0.f) ? 0x3F80u : 0u) | ((b != 0.f) ? 0x3F800000u : 0u);
}

// Decay powers
constexpr float DF1 = 0.95122942450071400910f;            // exp(-0.05)
constexpr float DF2 = DF1 * DF1;
constexpr float DF4 = DF2 * DF2;
constexpr float DF8 = DF4 * DF4;
constexpr float DF16 = DF8 * DF8;
constexpr float DF32 = DF16 * DF16;
constexpr float DF64 = DF32 * DF32;

constexpr float DX1 = 0.99014786386058731819f;            // exp(-1/101)
constexpr float DX2 = DX1 * DX1;
constexpr float DX4 = DX2 * DX2;
constexpr float DX8 = DX4 * DX4;
constexpr float DX16 = DX8 * DX8;
constexpr float DX32 = DX16 * DX16;
constexpr float DX64 = DX32 * DX32;

template <int K>
__device__ __forceinline__ float seg_step(float b, float pw, int sl) {
    float t = __shfl_up(b, K, 64);
    return (sl >= K) ? fmaf(pw, t, b) : b;
}
__device__ __forceinline__ float scan16(float c, float p1, float p2, float p4,
                                        float p8, int sl) {
    c = seg_step<1>(c, p1, sl);
    c = seg_step<2>(c, p2, sl);
    c = seg_step<4>(c, p4, sl);
    c = seg_step<8>(c, p8, sl);
    return c;
}
__device__ __forceinline__ float fold4(float4 u, float d) {
    float C = d * u.x;
    C = d * (C + u.y); C = d * (C + u.z); C = d * (C + u.w);
    return C;
}
__device__ __forceinline__ float4 expand4(float x, float4 u, float d) {
    float4 t;
    t.x = x; x = d * (x + u.x);
    t.y = x; x = d * (x + u.y);
    t.z = x; x = d * (x + u.z);
    t.w = x;
    return t;
}

// ---------------------------------------------------------------------------
// Stage 1 (slot-coalesced): 16 lanes per (b, neuron) row; lane sl owns
// timesteps 64j + 4sl..+3 for slots j=0..3; fully coalesced 256 B loads per
// segment. Per-slot affine fold -> four 16-lane Kogge-Stone scans -> serial
// cross-slot carry -> expand. Spike count: block reduce -> plain store to
// partials[blockIdx] (4096 slots, no memset dispatch, no atomics).
// ---------------------------------------------------------------------------
__global__ __launch_bounds__(256) void stage_traces(
    const float* __restrict__ pre, const float* __restrict__ post,
    const float* __restrict__ mApP, const float* __restrict__ mAmP,
    ushort_t* __restrict__ Ab, ushort_t* __restrict__ Bb,
    float* __restrict__ partials)
{
    const int tid  = threadIdx.x;
    const int lane = tid & 63;
    const int wv   = tid >> 6;
    const int sl   = lane & 15;
    const int rowg = blockIdx.x * 16 + wv * 4 + (lane >> 4);   // 0..65535
    const bool isPre = rowg < TB * NP;                         // block-uniform
    const int m = isPre ? rowg : rowg - TB * NP;
    const int b = m >> 11;
    const int r = m & 2047;

    const float4* srcRow = (const float4*)((isPre ? pre : post) + (size_t)m * TT);
    const float4 u0 = srcRow[sl];          // slot 0: t = 4sl..4sl+3
    const float4 u1 = srcRow[16 + sl];     // slot 1
    const float4 u2 = srcRow[32 + sl];     // slot 2
    const float4 u3 = srcRow[48 + sl];     // slot 3

    float cnt = ((u0.x + u0.y) + (u0.z + u0.w)) + ((u1.x + u1.y) + (u1.z + u1.w))
              + ((u2.x + u2.y) + (u2.z + u2.w)) + ((u3.x + u3.y) + (u3.z + u3.w));

    const int hi = lane | 15;

    // ---- fast-decay trace: per-slot scans + cross-slot carry ----
    float bf0 = scan16(fold4(u0, DF1), DF4, DF8, DF16, DF32, sl);
    float bf1_ = scan16(fold4(u1, DF1), DF4, DF8, DF16, DF32, sl);
    float bf2 = scan16(fold4(u2, DF1), DF4, DF8, DF16, DF32, sl);
    float bf3 = scan16(fold4(u3, DF1), DF4, DF8, DF16, DF32, sl);
    const float Tf0 = __shfl(bf0, hi, 64);
    const float Tf1 = __shfl(bf1_, hi, 64);
    const float Tf2 = __shfl(bf2, hi, 64);
    const float Xf1 = Tf0;
    const float Xf2 = fmaf(DF64, Xf1, Tf1);
    const float Xf3 = fmaf(DF64, Xf2, Tf2);
    float ef0 = __shfl_up(bf0, 1, 64);
    float ef1 = __shfl_up(bf1_, 1, 64);
    float ef2 = __shfl_up(bf2, 1, 64);
    float ef3 = __shfl_up(bf3, 1, 64);
    if (sl == 0) { ef0 = 0.f; ef1 = 0.f; ef2 = 0.f; ef3 = 0.f; }
    float pf = 1.f;
    if (sl & 1) pf *= DF4;
    if (sl & 2) pf *= DF8;
    if (sl & 4) pf *= DF16;
    if (sl & 8) pf *= DF32;
    const float4 t0 = expand4(ef0,                 u0, DF1);
    const float4 t1 = expand4(fmaf(pf, Xf1, ef1),  u1, DF1);
    const float4 t2 = expand4(fmaf(pf, Xf2, ef2),  u2, DF1);
    const float4 t3 = expand4(fmaf(pf, Xf3, ef3),  u3, DF1);

    ushort_t* oA = (isPre ? Ab : Bb) + (size_t)r * KT + b * TT + 4 * sl;

    if (isPre) {
        *(uint2*)(oA)            = uint2{pack2(t0.x, t0.y), pack2(t0.z, t0.w)};
        *(uint2*)(oA + 64)       = uint2{pack2(t1.x, t1.y), pack2(t1.z, t1.w)};
        *(uint2*)(oA + 128)      = uint2{pack2(t2.x, t2.y), pack2(t2.z, t2.w)};
        *(uint2*)(oA + 192)      = uint2{pack2(t3.x, t3.y), pack2(t3.z, t3.w)};
        *(uint2*)(oA + KH)       = uint2{spk2(u0.x, u0.y), spk2(u0.z, u0.w)};
        *(uint2*)(oA + KH + 64)  = uint2{spk2(u1.x, u1.y), spk2(u1.z, u1.w)};
        *(uint2*)(oA + KH + 128) = uint2{spk2(u2.x, u2.y), spk2(u2.z, u2.w)};
        *(uint2*)(oA + KH + 192) = uint2{spk2(u3.x, u3.y), spk2(u3.z, u3.w)};
    } else {
        // ---- slow (triplet) trace ----
        float bx0 = scan16(fold4(u0, DX1), DX4, DX8, DX16, DX32, sl);
        float bx1 = scan16(fold4(u1, DX1), DX4, DX8, DX16, DX32, sl);
        float bx2 = scan16(fold4(u2, DX1), DX4, DX8, DX16, DX32, sl);
        float bx3 = scan16(fold4(u3, DX1), DX4, DX8, DX16, DX32, sl);
        const float Tx0 = __shfl(bx0, hi, 64);
        const float Tx1 = __shfl(bx1, hi, 64);
        const float Tx2 = __shfl(bx2, hi, 64);
        const float Xx1 = Tx0;
        const float Xx2 = fmaf(DX64, Xx1, Tx1);
        const float Xx3 = fmaf(DX64, Xx2, Tx2);
        float ex0 = __shfl_up(bx0, 1, 64);
        float ex1 = __shfl_up(bx1, 1, 64);
        float ex2 = __shfl_up(bx2, 1, 64);
        float ex3 = __shfl_up(bx3, 1, 64);
        if (sl == 0) { ex0 = 0.f; ex1 = 0.f; ex2 = 0.f; ex3 = 0.f; }
        float px = 1.f;
        if (sl & 1) px *= DX4;
        if (sl & 2) px *= DX8;
        if (sl & 4) px *= DX16;
        if (sl & 8) px *= DX32;
        const float4 w0 = expand4(ex0,                u0, DX1);
        const float4 w1 = expand4(fmaf(px, Xx1, ex1), u1, DX1);
        const float4 w2 = expand4(fmaf(px, Xx2, ex2), u2, DX1);
        const float4 w3 = expand4(fmaf(px, Xx3, ex3), u3, DX1);

        const float Ap = *mApP;
        const float Am = *mAmP;
        auto av2 = [&](float sa, float ta, float sb, float tb) -> unsigned {
            unsigned lo = (sa != 0.f) ? bf1(fmaf(0.0065f, ta, Ap)) : 0u;
            unsigned hi2 = (sb != 0.f) ? bf1(fmaf(0.0065f, tb, Ap)) : 0u;
            return lo | (hi2 << 16);
        };
        *(uint2*)(oA)       = uint2{av2(u0.x, w0.x, u0.y, w0.y), av2(u0.z, w0.z, u0.w, w0.w)};
        *(uint2*)(oA + 64)  = uint2{av2(u1.x, w1.x, u1.y, w1.y), av2(u1.z, w1.z, u1.w, w1.w)};
        *(uint2*)(oA + 128) = uint2{av2(u2.x, w2.x, u2.y, w2.y), av2(u2.z, w2.z, u2.w, w2.w)};
        *(uint2*)(oA + 192) = uint2{av2(u3.x, w3.x, u3.y, w3.y), av2(u3.z, w3.z, u3.w, w3.w)};
        *(uint2*)(oA + KH)       = uint2{pack2(-Am * t0.x, -Am * t0.y), pack2(-Am * t0.z, -Am * t0.w)};
        *(uint2*)(oA + KH + 64)  = uint2{pack2(-Am * t1.x, -Am * t1.y), pack2(-Am * t1.z, -Am * t1.w)};
        *(uint2*)(oA + KH + 128) = uint2{pack2(-Am * t2.x, -Am * t2.y), pack2(-Am * t2.z, -Am * t2.w)};
        *(uint2*)(oA + KH + 192) = uint2{pack2(-Am * t3.x, -Am * t3.y), pack2(-Am * t3.z, -Am * t3.w)};
    }

    #pragma unroll
    for (int off = 32; off > 0; off >>= 1)
        cnt += __shfl_down(cnt, off, 64);
    __shared__ float wsum[4];
    if (lane == 0) wsum[wv] = cnt;
    __syncthreads();
    if (tid == 0)
        partials[blockIdx.x] = (wsum[0] + wsum[1]) + (wsum[2] + wsum[3]);
}

// ---------------------------------------------------------------------------
// Stage 2: split-K=2 GEMM (BK=64, double-buffered global_load_lds prefetch,
// hoisted incremental pointers, XOR LDS swizzle, XCD-patched grid of 512 =
// 2 blocks/CU; 904 TF effective = the m97-structure plateau). Block 0 also
// reduces the 4096 spike-count partials -> scaleBuf. z=0 -> d_out, z=1 -> ws.
// ---------------------------------------------------------------------------
__device__ __forceinline__ void async16(const ushort_t* g, ushort_t* l) {
    __builtin_amdgcn_global_load_lds(
        (const __attribute__((address_space(1))) unsigned int*)g,
        (__attribute__((address_space(3))) unsigned int*)l,
        16, 0, 0);
}

__global__ __launch_bounds__(256, 2) void gemm_split(
    const ushort_t* __restrict__ Ab, const ushort_t* __restrict__ Bb,
    const float* __restrict__ sp, float* __restrict__ scaleBuf,
    float* __restrict__ P0, float* __restrict__ P1)
{
    __shared__ ushort_t As[2][128 * 64];
    __shared__ ushort_t Bs[2][128 * 64];
    __shared__ float red[4];

    const int tid  = threadIdx.x;
    const int lane = tid & 63;
    const int wv   = tid >> 6;
    const int wr   = wv >> 1;
    const int wc   = wv & 1;
    const int quad = lane >> 4;
    const int m16  = lane & 15;

    // block 0: reduce the 4096 spike-count partials -> scale
    if (blockIdx.x == 0) {
        float v = 0.f;
        #pragma unroll
        for (int i = 0; i < 16; ++i) v += sp[tid + i * 256];
        #pragma unroll
        for (int off = 32; off > 0; off >>= 1)
            v += __shfl_down(v, off, 64);
        if (lane == 0) red[wv] = v;
        __syncthreads();
        if (tid == 0) {
            float s = (red[0] + red[1]) + (red[2] + red[3]);
            scaleBuf[0] = sqrtf(0.1f / (s * (1.0f / 4096.0f) + 1e-6f));
        }
    }

    // XCD swizzle: id&7 = XCD; fixed 4x8 (p,q) patch per XCD, z inner
    const int id  = blockIdx.x;
    const int xcd = id & 7;
    const int j5  = id >> 3;          // 0..63
    const int z   = j5 & 1;
    const int t   = j5 >> 1;          // 0..31
    const int pt  = ((xcd >> 1) << 2) + (t >> 3);   // 0..15
    const int qt  = ((xcd & 1) << 3) + (t & 7);     // 0..15

    const int p0 = pt * 128;
    const int q0 = qt * 128;
    const int kbase = z * (KT / 2);
    const int ldsbase = wv * 512;     // elements; wave-uniform

    const ushort_t* gaP[4];
    const ushort_t* gbP[4];
    #pragma unroll
    for (int rr = 0; rr < 4; ++rr) {
        const int c   = rr * 256 + tid;
        const int row = c >> 3;
        const int kk8 = (c & 7) ^ (row & 7);
        gaP[rr] = Ab + (size_t)(p0 + row) * KT + kbase + kk8 * 8;
        gbP[rr] = Bb + (size_t)(q0 + row) * KT + kbase + kk8 * 8;
    }

    f32x4 acc[4][4] = {};

    auto stageF = [&](int buf) {
        #pragma unroll
        for (int rr = 0; rr < 4; ++rr) {
            async16(gaP[rr], &As[buf][rr * 2048 + ldsbase]);
            async16(gbP[rr], &Bs[buf][rr * 2048 + ldsbase]);
            gaP[rr] += 64;
            gbP[rr] += 64;
        }
    };
    auto computeF = [&](int buf) {
        #pragma unroll
        for (int ks = 0; ks < 2; ++ks) {
            bf16x8 af[4], bfr[4];
            #pragma unroll
            for (int i = 0; i < 4; ++i) {
                const int row  = wr * 64 + i * 16 + m16;
                const int slot = (ks * 4 + quad) ^ (row & 7);
                af[i] = *(const bf16x8*)&As[buf][row * 64 + slot * 8];
            }
            #pragma unroll
            for (int jj = 0; jj < 4; ++jj) {
                const int row  = wc * 64 + jj * 16 + m16;
                const int slot = (ks * 4 + quad) ^ (row & 7);
                bfr[jj] = *(const bf16x8*)&Bs[buf][row * 64 + slot * 8];
            }
            #pragma unroll
            for (int i = 0; i < 4; ++i)
                #pragma unroll
                for (int jj = 0; jj < 4; ++jj)
                    acc[i][jj] = __builtin_amdgcn_mfma_f32_16x16x32_bf16(
                        af[i], bfr[jj], acc[i][jj], 0, 0, 0);
        }
    };

    constexpr int NIT = (KT / 2) / 64;   // 64 k-chunks, 32 double-iters
    stageF(0);
    for (int kt2 = 0; kt2 < NIT / 2; ++kt2) {
        __syncthreads();
        stageF(1);
        computeF(0);
        __syncthreads();
        if (kt2 + 1 < NIT / 2)
            stageF(0);
        computeF(1);
    }

    float* P = z ? P1 : P0;
    #pragma unroll
    for (int i = 0; i < 4; ++i) {
        const int prow = p0 + wr * 64 + i * 16 + quad * 4;
        #pragma unroll
        for (int jj = 0; jj < 4; ++jj) {
            const int qcol = q0 + wc * 64 + jj * 16 + m16;
            #pragma unroll
            for (int r2 = 0; r2 < 4; ++r2)
                P[(size_t)(prow + r2) * NQ + qcol] = acc[i][jj][r2];
        }
    }
}

// ---------------------------------------------------------------------------
// Stage 3: Out = clip(W + scale*(P0+P1), -2, 2); P0 lives in d_out (in-place).
// 67 MB traffic, at its BW floor (~11 us).
// ---------------------------------------------------------------------------
__global__ __launch_bounds__(256) void merge_out(
    const float* __restrict__ W, const float* __restrict__ P1,
    const float* __restrict__ scaleBuf, float* __restrict__ Out)
{
    const float scale = scaleBuf[0];
    const size_t i4 = (size_t)blockIdx.x * 256 + threadIdx.x;
    float4 w = ((const float4*)W)[i4];
    float4 a = ((const float4*)Out)[i4];
    float4 c = ((const float4*)P1)[i4];
    float4 o;
    o.x = fminf(fmaxf(fmaf(scale, a.x + c.x, w.x), -2.f), 2.f);
    o.y = fminf(fmaxf(fmaf(scale, a.y + c.y, w.y), -2.f), 2.f);
    o.z = fminf(fmaxf(fmaf(scale, a.z + c.z, w.z), -2.f), 2.f);
    o.w = fminf(fmaxf(fmaf(scale, a.w + c.w, w.w), -2.f), 2.f);
    ((float4*)Out)[i4] = o;
}

extern "C" void kernel_launch(void* const* d_in, const int* in_sizes, int n_in,
                              void* d_out, int out_size, void* d_ws, size_t ws_size,
                              hipStream_t stream) {
    const float* pre  = (const float*)d_in[0];
    const float* post = (const float*)d_in[1];
    const float* W    = (const float*)d_in[2];
    const float* mAp  = (const float*)d_in[3];
    const float* mAm  = (const float*)d_in[4];
    float* out = (float*)d_out;

    char* ws = (char*)d_ws;
    float* partials = (float*)ws;                                    // 16 KB (4096 slots)
    float* scaleBuf = (float*)(ws + 16384);
    ushort_t* Ab = (ushort_t*)(ws + 32768);                          // 33.6 MB
    ushort_t* Bb = (ushort_t*)(ws + 32768 + (size_t)NP * KT * 2);    // 33.6 MB
    float* P1    = (float*)(ws + 32768 + 2 * (size_t)NP * KT * 2);   // 16.8 MB

    stage_traces<<<dim3((TB * NP + TB * NQ) / 16), dim3(256), 0, stream>>>(
        pre, post, mAp, mAm, Ab, Bb, partials);

    gemm_split<<<dim3(512), dim3(256), 0, stream>>>(
        Ab, Bb, partials, scaleBuf, out, P1);

    merge_out<<<dim3(NP * NQ / 1024), dim3(256), 0, stream>>>(
        W, P1, scaleBuf, out);
}